// Round 3
// baseline (653.343 us; speedup 1.0000x reference)
//
#include <hip/hip_runtime.h>

// Problem constants (fixed by reference): B=2, N=8192, C=80
constexpr int NB = 2;
constexpr int NN = 8192;
constexpr int NC = 80;

// d_out layout (floats), in reference return order:
// boxes[B,N,4], max_scores[B,N], labels[B,N], keep[B,N], all_scores[B,N,C]
constexpr size_t OFF_BOXES  = 0;
constexpr size_t OFF_SCORES = (size_t)NB * NN * 4;            // 65536
constexpr size_t OFF_LABELS = OFF_SCORES + (size_t)NB * NN;   // 81920
constexpr size_t OFF_KEEP   = OFF_LABELS + (size_t)NB * NN;   // 98304
constexpr size_t OFF_ALL    = OFF_KEEP + (size_t)NB * NN;     // 114688

// d_ws layout
constexpr size_t WS_KEYS  = 0;                                  // B*N u64
constexpr size_t WS_VBYTE = WS_KEYS + (size_t)NB * NN * 8;      // B*N u8
constexpr size_t WS_ORDER = WS_VBYTE + (size_t)NB * NN;         // B*N i32
constexpr size_t WS_SBOX  = WS_ORDER + (size_t)NB * NN * 4;     // B*N float4
constexpr size_t WS_VBITS = WS_SBOX + (size_t)NB * NN * 16;     // B*128 u64
constexpr size_t WS_MASK  = WS_VBITS + (size_t)NB * 128 * 8;    // B*N*128 u64
constexpr size_t WS_TOTAL = WS_MASK + (size_t)NB * NN * 128 * 8; // ~17.25 MB

// IoU exactly mirroring the numpy op order; contraction off so f32 rounding
// matches numpy bit-for-bit (keep bits tolerate no error).
__device__ inline float iou_pair(const float4 p, const float4 q) {
#pragma clang fp contract(off)
  float areaA = (p.z - p.x) * (p.w - p.y);
  float areaB = (q.z - q.x) * (q.w - q.y);
  float ix1 = fmaxf(p.x, q.x);
  float iy1 = fmaxf(p.y, q.y);
  float ix2 = fminf(p.z, q.z);
  float iy2 = fminf(p.w, q.w);
  float inter = fmaxf(ix2 - ix1, 0.0f) * fmaxf(iy2 - iy1, 0.0f);
  float uni = areaA + areaB - inter;
  return inter / fmaxf(uni, 1e-9f);
}

__device__ inline float clip01(float v) { return fminf(fmaxf(v, 0.0f), 1.0f); }

__device__ inline unsigned long long readlane64(unsigned long long v, int src) {
  unsigned int lo = (unsigned int)__builtin_amdgcn_readlane((int)(unsigned int)v, src);
  unsigned int hi = (unsigned int)__builtin_amdgcn_readlane((int)(unsigned int)(v >> 32), src);
  return ((unsigned long long)hi << 32) | lo;
}

__device__ inline unsigned long long xorshfl_or64(unsigned long long v) {
  // OR-reduce across the executing wave (butterfly); result uniform.
  for (int off = 32; off; off >>= 1) {
    unsigned int lo = (unsigned int)__shfl_xor((int)(unsigned int)v, off, 64);
    unsigned int hi = (unsigned int)__shfl_xor((int)(unsigned int)(v >> 32), off, 64);
    v |= ((unsigned long long)hi << 32) | lo;
  }
  return v;
}

// One wave per (b,n): sigmoid all 80 classes, max/argmax (first-index ties),
// box decode, validity, sort key.
__global__ __launch_bounds__(256) void decode_kernel(
    const float* __restrict__ logits, const float4* __restrict__ deltas,
    const float4* __restrict__ anchors, float4* __restrict__ boxes_out,
    float* __restrict__ scores_out, float* __restrict__ labels_out,
    float* __restrict__ all_out, unsigned long long* __restrict__ keys,
    unsigned char* __restrict__ vbyte) {
#pragma clang fp contract(off)
  int wid = (blockIdx.x * 256 + threadIdx.x) >> 6;  // 0 .. B*N-1
  int lane = threadIdx.x & 63;
  int n = wid & (NN - 1);
  size_t base = (size_t)wid * NC;

  float x0 = logits[base + lane];
  float sig0 = 1.0f / (1.0f + expf(-x0));
  all_out[base + lane] = sig0;
  float bs = sig0;
  int bidx = lane;
  if (lane < NC - 64) {
    float x1 = logits[base + 64 + lane];
    float sig1 = 1.0f / (1.0f + expf(-x1));
    all_out[base + 64 + lane] = sig1;
    if (sig1 > bs) { bs = sig1; bidx = lane + 64; }  // tie -> smaller idx wins
  }
  for (int off = 32; off; off >>= 1) {
    float os = __shfl_xor(bs, off, 64);
    int oi = __shfl_xor(bidx, off, 64);
    if (os > bs || (os == bs && oi < bidx)) { bs = os; bidx = oi; }
  }
  if (lane == 0) {
    float4 d = deltas[wid];
    float4 a = anchors[n];
    float aw = a.z - a.x, ah = a.w - a.y;
    float acx = a.x + 0.5f * aw, acy = a.y + 0.5f * ah;
    float dw = fminf(d.z, 4.0f), dh = fminf(d.w, 4.0f);
    float pcx = d.x * aw + acx;
    float pcy = d.y * ah + acy;
    float pw = expf(dw) * aw;
    float ph = expf(dh) * ah;
    float4 bx;
    bx.x = clip01(pcx - 0.5f * pw);
    bx.y = clip01(pcy - 0.5f * ph);
    bx.z = clip01(pcx + 0.5f * pw);
    bx.w = clip01(pcy + 0.5f * ph);
    boxes_out[wid] = bx;
    scores_out[wid] = bs;
    labels_out[wid] = (float)bidx;
    float bw = bx.z - bx.x, bh = bx.w - bx.y;
    bool valid = (bs > 0.5f) && (bw > 0.01f) && (bh > 0.01f) &&
                 (bw < 0.99f) && (bh < 0.99f);
    vbyte[wid] = valid ? 1 : 0;
    // score bits monotone (score>0); tie-break: smaller n first under
    // DESCENDING key sort -> use (N-1-n) in low bits.
    keys[wid] = ((unsigned long long)__float_as_uint(bs) << 32) |
                (unsigned int)(NN - 1 - n);
  }
}

// Per-batch bitonic sort (descending) of 8192 u64 keys in LDS; then emit
// order[], gathered sorted boxes, and valid bitmask in sorted order.
__global__ __launch_bounds__(1024) void sort_kernel(
    const unsigned long long* __restrict__ keys_in,
    const float4* __restrict__ boxes, const unsigned char* __restrict__ vbyte,
    int* __restrict__ order, float4* __restrict__ sbox,
    unsigned long long* __restrict__ vbits) {
  __shared__ unsigned long long sk[NN];  // 64 KiB
  int b = blockIdx.x, tid = threadIdx.x;
  for (int p = tid; p < NN; p += 1024) sk[p] = keys_in[(size_t)b * NN + p];
  __syncthreads();
  for (int k = 2; k <= NN; k <<= 1) {
    for (int j = k >> 1; j > 0; j >>= 1) {
      for (int i = tid; i < NN; i += 1024) {
        int ixj = i ^ j;
        if (ixj > i) {
          unsigned long long a = sk[i], c = sk[ixj];
          bool up = (i & k) == 0;  // descending region
          if (up ? (a < c) : (a > c)) { sk[i] = c; sk[ixj] = a; }
        }
      }
      __syncthreads();
    }
  }
  for (int p = tid; p < NN; p += 1024) {
    unsigned long long key = sk[p];
    int idx = (NN - 1) - (int)(unsigned int)(key & 0xffffffffull);
    order[(size_t)b * NN + p] = idx;
    sbox[(size_t)b * NN + p] = boxes[(size_t)b * NN + idx];
    unsigned long long ball = __ballot(vbyte[(size_t)b * NN + idx] != 0);
    if ((tid & 63) == 0) vbits[b * 128 + (p >> 6)] = ball;
  }
}

// 64x64 tile of the (sorted-order) suppression matrix: bit j set in row i's
// word iff j>i and IoU>0.5. Upper triangle only.
__global__ __launch_bounds__(64) void build_kernel(
    const float4* __restrict__ sbox, unsigned long long* __restrict__ mask) {
  int bx = blockIdx.x, by = blockIdx.y, b = blockIdx.z;
  if (bx < by) return;
  int lane = threadIdx.x;
  __shared__ float4 cb[64];
  cb[lane] = sbox[(size_t)b * NN + bx * 64 + lane];
  __syncthreads();
  int i = by * 64 + lane;
  float4 rb = sbox[(size_t)b * NN + i];
  unsigned long long word = 0;
  int j0 = (bx == by) ? lane + 1 : 0;
  for (int jj = j0; jj < 64; ++jj)
    if (iou_pair(rb, cb[jj]) > 0.5f) word |= 1ull << jj;
  mask[((size_t)b * NN + i) * 128 + bx] = word;
}

// Greedy reduce v3: one 1024-thread block per batch, ONE barrier per chunk,
// no memory latency on the critical path.
//  - Wave 0 prefetches, 2 chunks ahead, BOTH the diag word (word c of rows in
//    chunk c) and the critical next word (word c+1 of rows in chunk c).
//  - After the serial bit-loop picks chunk c's kept set, the contribution of
//    those rows to remv[c+1] is a register butterfly-OR (no loads).
//  - Background (all 16 waves) runs ONE CHUNK BEHIND: during chunk c it ORs
//    rowlist[c-1]'s mask words w >= c+1 into s_remv (word c was already
//    covered by the carried critical OR). Deadline for word w is chunk w —
//    always met with >= 1 chunk of slack, so these loads overlap compute.
__global__ __launch_bounds__(1024) void reduce_kernel(
    const unsigned long long* __restrict__ mask,
    const unsigned long long* __restrict__ vbits,
    const int* __restrict__ order, float* __restrict__ keep_out) {
  int b = blockIdx.x, tid = threadIdx.x;
  int lane = tid & 63;
  bool w0 = tid < 64;
  __shared__ unsigned long long s_remv[128];
  __shared__ unsigned long long s_keep[128];
  __shared__ unsigned long long s_vbits[128];
  __shared__ int s_rowlist[2][64];
  __shared__ int s_nk[2];
  const unsigned long long* mb = mask + (size_t)b * NN * 128;

  for (int w = tid; w < 128; w += 1024) {
    s_remv[w] = 0ull;
    s_vbits[w] = vbits[b * 128 + w];
  }
  if (tid < 2) s_nk[tid] = 0;

  // Pipeline regs (wave 0): chunk c -> dA (diag word), nA (word c+1);
  // chunk c+1 -> dB, nB.
  unsigned long long dA = 0, nA = 0, dB = 0, nB = 0;
  unsigned long long crit = 0;  // kept-rows-of-previous-chunk OR into word c
  if (w0) {
    const unsigned long long* r0 = mb + (size_t)lane * 128;
    const unsigned long long* r1 = mb + (size_t)(64 + lane) * 128;
    dA = r0[0]; nA = r0[1];
    dB = r1[1]; nB = r1[2];
  }
  __syncthreads();

  for (int c = 0; c < 128; ++c) {
    int nk_prev = (c > 0) ? s_nk[(c - 1) & 1] : 0;
    if (w0) {
      // prefetch chunk c+2 (diag + critical-next), 2 chunks ahead
      unsigned long long dC = 0, nC = 0;
      if (c + 2 < 128) {
        const unsigned long long* rp = mb + (size_t)((c + 2) * 64 + lane) * 128;
        dC = rp[c + 2];
        if (c + 3 < 128) nC = rp[c + 3];
      }
      unsigned long long rm = s_remv[c] | crit;
      unsigned long long cand = s_vbits[c] & ~rm;  // uniform across wave 0
      unsigned int dl = (unsigned int)dA, dh = (unsigned int)(dA >> 32);
      unsigned long long kept = 0;
      while (cand) {  // uniform loop; bi wave-uniform -> readlane legal
        int bi = __builtin_ctzll(cand);
        unsigned long long rd =
            ((unsigned long long)(unsigned int)
                 __builtin_amdgcn_readlane((int)dh, bi) << 32) |
            (unsigned int)__builtin_amdgcn_readlane((int)dl, bi);
        kept |= 1ull << bi;
        cand = (cand - 1) & cand & ~rd;
      }
      // register-only contribution of chunk c's kept rows to remv word c+1
      crit = xorshfl_or64(((kept >> lane) & 1) ? nA : 0ull);
      if (lane == 0) {
        s_keep[c] = kept;
        s_nk[c & 1] = __popcll(kept);
      }
      if ((kept >> lane) & 1) {
        int pos = __popcll(kept & ((1ull << lane) - 1ull));
        s_rowlist[c & 1][pos] = c * 64 + lane;
      }
      dA = dB; nA = nB;
      dB = dC; nB = nC;
    }
    // Background: OR rowlist[c-1] rows into words >= c+1 (word c handled by
    // the carried crit). Loads overlap wave 0's serial phase.
    if (nk_prev > 0) {
      int w = tid & 127;  // word index
      int g = tid >> 7;   // row slot stride-8
      if (w > c) {
        const int* rl = s_rowlist[(c - 1) & 1];
        unsigned long long acc = 0;
        for (int k = g; k < nk_prev; k += 8)
          acc |= mb[(size_t)rl[k] * 128 + w];
        if (acc) atomicOr(&s_remv[w], acc);
      }
    }
    __syncthreads();
  }

  // scatter keep flags back to original anchor order (all 1024 threads)
  for (int p = tid; p < NN; p += 1024) {
    int orig = order[(size_t)b * NN + p];
    keep_out[(size_t)b * NN + orig] =
        ((s_keep[p >> 6] >> (p & 63)) & 1) ? 1.0f : 0.0f;
  }
}

// Slow-but-correct fallback if d_ws can't hold the 16 MB mask: classic
// iterative greedy NMS, one block per batch.
__global__ __launch_bounds__(1024) void nms_fallback(
    const float4* __restrict__ sbox, const unsigned long long* __restrict__ vbits,
    const int* __restrict__ order, float* __restrict__ keep_out) {
  int b = blockIdx.x, tid = threadIdx.x;
  __shared__ unsigned long long dead[128];
  __shared__ int s_next;
  __shared__ float4 s_box;
  for (int w = tid; w < 128; w += 1024) dead[w] = ~vbits[b * 128 + w];
  for (int p = tid; p < NN; p += 1024)
    keep_out[(size_t)b * NN + order[(size_t)b * NN + p]] = 0.0f;
  __syncthreads();
  int i = 0;
  while (true) {
    if (tid == 0) {
      int nxt = NN;
      int w = i >> 6;
      unsigned long long live = ~dead[w] & (~0ull << (i & 63));
      while (true) {
        if (live) { nxt = w * 64 + __builtin_ctzll(live); break; }
        if (++w >= 128) break;
        live = ~dead[w];
      }
      s_next = nxt;
      if (nxt < NN) {
        s_box = sbox[(size_t)b * NN + nxt];
        keep_out[(size_t)b * NN + order[(size_t)b * NN + nxt]] = 1.0f;
      }
    }
    __syncthreads();
    i = s_next;
    if (i >= NN) break;
    float4 kb = s_box;
    for (int j = i + 1 + tid; j < NN; j += 1024) {
      if (iou_pair(kb, sbox[(size_t)b * NN + j]) > 0.5f)
        atomicOr(&dead[j >> 6], 1ull << (j & 63));
    }
    __syncthreads();
    i = i + 1;
  }
}

extern "C" void kernel_launch(void* const* d_in, const int* in_sizes, int n_in,
                              void* d_out, int out_size, void* d_ws, size_t ws_size,
                              hipStream_t stream) {
  const float* logits = (const float*)d_in[0];
  const float4* deltas = (const float4*)d_in[1];
  const float4* anchors = (const float4*)d_in[2];
  float* out = (float*)d_out;
  float4* boxes_out = (float4*)(out + OFF_BOXES);
  float* scores_out = out + OFF_SCORES;
  float* labels_out = out + OFF_LABELS;
  float* keep_out = out + OFF_KEEP;
  float* all_out = out + OFF_ALL;

  char* ws = (char*)d_ws;
  unsigned long long* keys = (unsigned long long*)(ws + WS_KEYS);
  unsigned char* vbyte = (unsigned char*)(ws + WS_VBYTE);
  int* order = (int*)(ws + WS_ORDER);
  float4* sbox = (float4*)(ws + WS_SBOX);
  unsigned long long* vbits = (unsigned long long*)(ws + WS_VBITS);
  unsigned long long* mask = (unsigned long long*)(ws + WS_MASK);

  decode_kernel<<<dim3(NB * NN / 4), dim3(256), 0, stream>>>(
      logits, deltas, anchors, boxes_out, scores_out, labels_out, all_out,
      keys, vbyte);
  sort_kernel<<<dim3(NB), dim3(1024), 0, stream>>>(
      keys, (const float4*)boxes_out, vbyte, order, sbox, vbits);
  if (ws_size >= WS_TOTAL) {
    build_kernel<<<dim3(128, 128, NB), dim3(64), 0, stream>>>(sbox, mask);
    reduce_kernel<<<dim3(NB), dim3(1024), 0, stream>>>(mask, vbits, order, keep_out);
  } else {
    nms_fallback<<<dim3(NB), dim3(1024), 0, stream>>>(sbox, vbits, order, keep_out);
  }
}

// Round 4
// 541.859 us; speedup vs baseline: 1.2057x; 1.2057x over previous
//
#include <hip/hip_runtime.h>

// Problem constants (fixed by reference): B=2, N=8192, C=80
constexpr int NB = 2;
constexpr int NN = 8192;
constexpr int NC = 80;
constexpr int ROWS = NN + 1;  // mask rows per batch; row NN is an all-zero row

// d_out layout (floats), in reference return order:
// boxes[B,N,4], max_scores[B,N], labels[B,N], keep[B,N], all_scores[B,N,C]
constexpr size_t OFF_BOXES  = 0;
constexpr size_t OFF_SCORES = (size_t)NB * NN * 4;
constexpr size_t OFF_LABELS = OFF_SCORES + (size_t)NB * NN;
constexpr size_t OFF_KEEP   = OFF_LABELS + (size_t)NB * NN;
constexpr size_t OFF_ALL    = OFF_KEEP + (size_t)NB * NN;

// d_ws layout
constexpr size_t WS_KEYS  = 0;                                   // B*N u64
constexpr size_t WS_VBYTE = WS_KEYS + (size_t)NB * NN * 8;       // B*N u8
constexpr size_t WS_ORDER = WS_VBYTE + (size_t)NB * NN;          // B*N i32
constexpr size_t WS_SBOX  = WS_ORDER + (size_t)NB * NN * 4;      // B*N float4
constexpr size_t WS_VBITS = WS_SBOX + (size_t)NB * NN * 16;      // B*128 u64
constexpr size_t WS_MASK  = WS_VBITS + (size_t)NB * 128 * 8;     // B*ROWS*128 u64
constexpr size_t WS_TOTAL = WS_MASK + (size_t)NB * ROWS * 128 * 8;

typedef unsigned long long u64;

// lgkmcnt(0)-only barrier: keeps global loads in flight across it.
// simm16: vmcnt[3:0]=0xF, expcnt=7<<4, lgkmcnt=0<<8, vmcnt[5:4]=3<<14 -> 0xC07F
__device__ inline void lbar() {
  __builtin_amdgcn_s_waitcnt(0xc07f);
  __builtin_amdgcn_s_barrier();
}

// IoU exactly mirroring the numpy op order; contraction off so f32 rounding
// matches numpy bit-for-bit (keep bits tolerate no error).
__device__ inline float iou_pair(const float4 p, const float4 q) {
#pragma clang fp contract(off)
  float areaA = (p.z - p.x) * (p.w - p.y);
  float areaB = (q.z - q.x) * (q.w - q.y);
  float ix1 = fmaxf(p.x, q.x);
  float iy1 = fmaxf(p.y, q.y);
  float ix2 = fminf(p.z, q.z);
  float iy2 = fminf(p.w, q.w);
  float inter = fmaxf(ix2 - ix1, 0.0f) * fmaxf(iy2 - iy1, 0.0f);
  float uni = areaA + areaB - inter;
  return inter / fmaxf(uni, 1e-9f);
}

__device__ inline float clip01(float v) { return fminf(fmaxf(v, 0.0f), 1.0f); }

// One wave per (b,n): sigmoid all 80 classes, max/argmax (first-index ties),
// box decode, validity, sort key. Also zero-inits vbits (scattered into by
// rank_kernel's atomicOr).
__global__ __launch_bounds__(256) void decode_kernel(
    const float* __restrict__ logits, const float4* __restrict__ deltas,
    const float4* __restrict__ anchors, float4* __restrict__ boxes_out,
    float* __restrict__ scores_out, float* __restrict__ labels_out,
    float* __restrict__ all_out, u64* __restrict__ keys,
    unsigned char* __restrict__ vbyte, u64* __restrict__ vbits) {
#pragma clang fp contract(off)
  if (blockIdx.x == 0 && threadIdx.x < NB * 128) vbits[threadIdx.x] = 0ull;
  int wid = (blockIdx.x * 256 + threadIdx.x) >> 6;  // 0 .. B*N-1
  int lane = threadIdx.x & 63;
  int n = wid & (NN - 1);
  size_t base = (size_t)wid * NC;

  float x0 = logits[base + lane];
  float sig0 = 1.0f / (1.0f + expf(-x0));
  all_out[base + lane] = sig0;
  float bs = sig0;
  int bidx = lane;
  if (lane < NC - 64) {
    float x1 = logits[base + 64 + lane];
    float sig1 = 1.0f / (1.0f + expf(-x1));
    all_out[base + 64 + lane] = sig1;
    if (sig1 > bs) { bs = sig1; bidx = lane + 64; }  // tie -> smaller idx wins
  }
  for (int off = 32; off; off >>= 1) {
    float os = __shfl_xor(bs, off, 64);
    int oi = __shfl_xor(bidx, off, 64);
    if (os > bs || (os == bs && oi < bidx)) { bs = os; bidx = oi; }
  }
  if (lane == 0) {
    float4 d = deltas[wid];
    float4 a = anchors[n];
    float aw = a.z - a.x, ah = a.w - a.y;
    float acx = a.x + 0.5f * aw, acy = a.y + 0.5f * ah;
    float dw = fminf(d.z, 4.0f), dh = fminf(d.w, 4.0f);
    float pcx = d.x * aw + acx;
    float pcy = d.y * ah + acy;
    float pw = expf(dw) * aw;
    float ph = expf(dh) * ah;
    float4 bx;
    bx.x = clip01(pcx - 0.5f * pw);
    bx.y = clip01(pcy - 0.5f * ph);
    bx.z = clip01(pcx + 0.5f * pw);
    bx.w = clip01(pcy + 0.5f * ph);
    boxes_out[wid] = bx;
    scores_out[wid] = bs;
    labels_out[wid] = (float)bidx;
    float bw = bx.z - bx.x, bh = bx.w - bx.y;
    bool valid = (bs > 0.5f) && (bw > 0.01f) && (bh > 0.01f) &&
                 (bw < 0.99f) && (bh < 0.99f);
    vbyte[wid] = valid ? 1 : 0;
    // score bits monotone (score>0); tie-break: smaller n first under
    // DESCENDING key sort -> (N-1-n) in low bits. Keys are UNIQUE.
    keys[wid] = ((u64)__float_as_uint(bs) << 32) | (unsigned int)(NN - 1 - n);
  }
}

// Rank sort: rank_i = #{j: key_j > key_i} (keys unique -> permutation).
// Block = 1024 threads = 256 rows x 4 column-quarters; column index is
// wave-uniform -> key loads scalarize. Replaces the single-block bitonic.
__global__ __launch_bounds__(1024) void rank_kernel(
    const u64* __restrict__ keys, const float4* __restrict__ boxes,
    const unsigned char* __restrict__ vbyte, int* __restrict__ order,
    float4* __restrict__ sbox, u64* __restrict__ vbits) {
  int b = blockIdx.y;
  int r = threadIdx.x & 255;   // row slot
  int q = threadIdx.x >> 8;    // column quarter 0..3
  int i = blockIdx.x * 256 + r;
  const u64* kb = keys + (size_t)b * NN;
  u64 myk = kb[i];
  int cnt = 0;
  int j0 = q * (NN / 4), j1 = j0 + NN / 4;
#pragma unroll 8
  for (int j = j0; j < j1; ++j) {
    u64 kj = kb[j];  // wave-uniform address -> scalar load
    cnt += (kj > myk) ? 1 : 0;
  }
  __shared__ unsigned short part[4][256];
  part[q][r] = (unsigned short)cnt;
  __syncthreads();
  if (threadIdx.x < 256) {
    int rank = part[0][r] + part[1][r] + part[2][r] + part[3][r];
    order[(size_t)b * NN + rank] = i;
    sbox[(size_t)b * NN + rank] = boxes[(size_t)b * NN + i];
    if (vbyte[(size_t)b * NN + i])
      atomicOr(&vbits[b * 128 + (rank >> 6)], 1ull << (rank & 63));
  }
}

// 64x64 tile of the (sorted-order) suppression matrix: bit j set in row i's
// word iff j>i and IoU>0.5. Upper triangle only. Row stride padded: ROWS.
__global__ __launch_bounds__(64) void build_kernel(
    const float4* __restrict__ sbox, u64* __restrict__ mask) {
  int bx = blockIdx.x, by = blockIdx.y, b = blockIdx.z;
  if (bx < by) return;
  int lane = threadIdx.x;
  __shared__ float4 cb[64];
  cb[lane] = sbox[(size_t)b * NN + bx * 64 + lane];
  __syncthreads();
  int i = by * 64 + lane;
  float4 rb = sbox[(size_t)b * NN + i];
  u64 word = 0;
  int j0 = (bx == by) ? lane + 1 : 0;
  for (int jj = j0; jj < 64; ++jj)
    if (iou_pair(rb, cb[jj]) > 0.5f) word |= 1ull << jj;
  mask[((size_t)b * ROWS + i) * 128 + bx] = word;
}

// Greedy reduce v4: one 1024-thread block per batch, ONE light barrier
// (lgkmcnt-only) per chunk; background loads stay in flight across it.
//  - Wave 0: serial bit-loop (readlane broadcasts of the prefetched diag
//    word); kept lanes deposit their words c+1, c+2 into s_remv via LDS
//    atomicOr (no cross-lane butterfly).
//  - Background (all 16 waves): at chunk c ISSUE fixed-trip loads (4 rows x
//    ulonglong2, rowlist padded with the zero row NN) of rowlist[c-1]'s mask
//    words, CONSUME them at chunk c+1 into words > c+1. Full-chunk latency
//    hiding; coverage: wave0 covers words k+1,k+2 of chunk-k rows,
//    background covers words >= k+3 (consumed at chunk k+2, cond w > k+2).
__global__ __launch_bounds__(1024) void reduce_kernel(
    u64* __restrict__ mask, const u64* __restrict__ vbits,
    const int* __restrict__ order, float* __restrict__ keep_out) {
  int b = blockIdx.x, tid = threadIdx.x;
  int lane = tid & 63, wave = tid >> 6;
  __shared__ u64 s_remv[128];
  __shared__ u64 s_keep[128];
  __shared__ u64 s_vbits[128];
  __shared__ int s_rowlist[2][64];
  __shared__ int s_nk[2];
  u64* mbz = mask + (size_t)b * ROWS * 128;
  const u64* mb = mbz;

  for (int w = tid; w < 128; w += 1024) {
    s_remv[w] = 0ull;
    s_vbits[w] = vbits[b * 128 + w];
    mbz[(size_t)NN * 128 + w] = 0ull;  // zero row (padded rowlist target)
  }
  if (tid < 2) s_nk[tid] = 0;
  if (tid < 128) s_rowlist[tid >> 6][tid & 63] = NN;

  // Wave0 prefetch pipeline: chunk c -> d=word c (diag), n=word c+1, m=word c+2
  u64 dA = 0, nA = 0, mA = 0, dB = 0, nB = 0, mB = 0;
  if (wave == 0) {
    const u64* r0 = mb + (size_t)lane * 128;
    dA = r0[0]; nA = r0[1]; mA = r0[2];
    const u64* r1 = mb + (size_t)(64 + lane) * 128;
    dB = r1[1]; nB = r1[2]; mB = r1[3];
  }
  // Background pipeline registers (4 row-slots x 2 words)
  u64 t0x = 0, t0y = 0, t1x = 0, t1y = 0, t2x = 0, t2y = 0, t3x = 0, t3y = 0;
  int w0i = 2 * lane, w1i = 2 * lane + 1;
  __syncthreads();  // full barrier: zero-row global write + LDS init visible

  for (int c = 0; c < 128; ++c) {
    // Phase A: consume t (rows of chunk c-2) into words > c
    {
      u64 ax = t0x | t1x | t2x | t3x;
      u64 ay = t0y | t1y | t2y | t3y;
      if (w0i > c && ax) atomicOr(&s_remv[w0i], ax);
      if (w1i > c && ay) atomicOr(&s_remv[w1i], ay);
    }
    // Phase B: issue loads for rows of chunk c-1 (consumed at c+1, words >c+1)
    {
      int nk1 = s_nk[(c - 1) & 1];  // c=0 -> slot 1 = 0
      t0x = t0y = t1x = t1y = t2x = t2y = t3x = t3y = 0;
      if (nk1 > 0 && w1i > c + 1) {
        const int* rl = s_rowlist[(c - 1) & 1];
        int r0 = rl[wave], r1 = rl[wave + 16], r2 = rl[wave + 32],
            r3 = rl[wave + 48];
        const ulonglong2* p0 = (const ulonglong2*)(mb + (size_t)r0 * 128 + w0i);
        const ulonglong2* p1 = (const ulonglong2*)(mb + (size_t)r1 * 128 + w0i);
        const ulonglong2* p2 = (const ulonglong2*)(mb + (size_t)r2 * 128 + w0i);
        const ulonglong2* p3 = (const ulonglong2*)(mb + (size_t)r3 * 128 + w0i);
        ulonglong2 v0 = *p0, v1 = *p1, v2 = *p2, v3 = *p3;
        t0x = v0.x; t0y = v0.y; t1x = v1.x; t1y = v1.y;
        t2x = v2.x; t2y = v2.y; t3x = v3.x; t3y = v3.y;
      }
    }
    // Phase C (wave 0): serial greedy for chunk c
    if (wave == 0) {
      u64 rm = s_remv[c];
      u64 cand = s_vbits[c] & ~rm;  // uniform across wave 0
      u64 kept = 0;
      unsigned int dl = (unsigned int)dA, dh = (unsigned int)(dA >> 32);
      while (cand) {  // uniform loop; bi wave-uniform -> readlane legal
        int bi = __builtin_ctzll(cand);
        u64 rd = (((u64)(unsigned int)__builtin_amdgcn_readlane((int)dh, bi))
                  << 32) |
                 (unsigned int)__builtin_amdgcn_readlane((int)dl, bi);
        kept |= 1ull << bi;
        cand = (cand - 1) & cand & ~rd;
      }
      bool isk = (kept >> lane) & 1;
      if (c + 1 < 128 && isk && nA) atomicOr(&s_remv[c + 1], nA);
      if (c + 2 < 128 && isk && mA) atomicOr(&s_remv[c + 2], mA);
      s_rowlist[c & 1][lane] = NN;  // pad; kept positions overwrite below
      if (isk) {
        int pos = __popcll(kept & ((1ull << lane) - 1ull));
        s_rowlist[c & 1][pos] = c * 64 + lane;
      }
      if (lane == 0) {
        s_keep[c] = kept;
        s_nk[c & 1] = __popcll(kept);
      }
      // prefetch chunk c+2
      u64 dC = 0, nC = 0, mC = 0;
      if (c + 2 < 128) {
        const u64* rp = mb + (size_t)((c + 2) * 64 + lane) * 128;
        dC = rp[c + 2];
        nC = (c + 3 < 128) ? rp[c + 3] : 0;
        mC = (c + 4 < 128) ? rp[c + 4] : 0;
      }
      dA = dB; nA = nB; mA = mB;
      dB = dC; nB = nC; mB = mC;
    }
    lbar();  // lgkm-only: LDS ordered, global loads stay in flight
  }

  // scatter keep flags back to original anchor order
  for (int p = tid; p < NN; p += 1024) {
    int orig = order[(size_t)b * NN + p];
    keep_out[(size_t)b * NN + orig] =
        ((s_keep[p >> 6] >> (p & 63)) & 1) ? 1.0f : 0.0f;
  }
}

// Slow-but-correct fallback if d_ws can't hold the mask: classic iterative
// greedy NMS, one block per batch.
__global__ __launch_bounds__(1024) void nms_fallback(
    const float4* __restrict__ sbox, const u64* __restrict__ vbits,
    const int* __restrict__ order, float* __restrict__ keep_out) {
  int b = blockIdx.x, tid = threadIdx.x;
  __shared__ u64 dead[128];
  __shared__ int s_next;
  __shared__ float4 s_box;
  for (int w = tid; w < 128; w += 1024) dead[w] = ~vbits[b * 128 + w];
  for (int p = tid; p < NN; p += 1024)
    keep_out[(size_t)b * NN + order[(size_t)b * NN + p]] = 0.0f;
  __syncthreads();
  int i = 0;
  while (true) {
    if (tid == 0) {
      int nxt = NN;
      int w = i >> 6;
      u64 live = ~dead[w] & (~0ull << (i & 63));
      while (true) {
        if (live) { nxt = w * 64 + __builtin_ctzll(live); break; }
        if (++w >= 128) break;
        live = ~dead[w];
      }
      s_next = nxt;
      if (nxt < NN) {
        s_box = sbox[(size_t)b * NN + nxt];
        keep_out[(size_t)b * NN + order[(size_t)b * NN + nxt]] = 1.0f;
      }
    }
    __syncthreads();
    i = s_next;
    if (i >= NN) break;
    float4 kb = s_box;
    for (int j = i + 1 + tid; j < NN; j += 1024) {
      if (iou_pair(kb, sbox[(size_t)b * NN + j]) > 0.5f)
        atomicOr(&dead[j >> 6], 1ull << (j & 63));
    }
    __syncthreads();
    i = i + 1;
  }
}

extern "C" void kernel_launch(void* const* d_in, const int* in_sizes, int n_in,
                              void* d_out, int out_size, void* d_ws, size_t ws_size,
                              hipStream_t stream) {
  const float* logits = (const float*)d_in[0];
  const float4* deltas = (const float4*)d_in[1];
  const float4* anchors = (const float4*)d_in[2];
  float* out = (float*)d_out;
  float4* boxes_out = (float4*)(out + OFF_BOXES);
  float* scores_out = out + OFF_SCORES;
  float* labels_out = out + OFF_LABELS;
  float* keep_out = out + OFF_KEEP;
  float* all_out = out + OFF_ALL;

  char* ws = (char*)d_ws;
  u64* keys = (u64*)(ws + WS_KEYS);
  unsigned char* vbyte = (unsigned char*)(ws + WS_VBYTE);
  int* order = (int*)(ws + WS_ORDER);
  float4* sbox = (float4*)(ws + WS_SBOX);
  u64* vbits = (u64*)(ws + WS_VBITS);
  u64* mask = (u64*)(ws + WS_MASK);

  decode_kernel<<<dim3(NB * NN / 4), dim3(256), 0, stream>>>(
      logits, deltas, anchors, boxes_out, scores_out, labels_out, all_out,
      keys, vbyte, vbits);
  rank_kernel<<<dim3(NN / 256, NB), dim3(1024), 0, stream>>>(
      keys, (const float4*)boxes_out, vbyte, order, sbox, vbits);
  if (ws_size >= WS_TOTAL) {
    build_kernel<<<dim3(128, 128, NB), dim3(64), 0, stream>>>(sbox, mask);
    reduce_kernel<<<dim3(NB), dim3(1024), 0, stream>>>(mask, vbits, order,
                                                       keep_out);
  } else {
    nms_fallback<<<dim3(NB), dim3(1024), 0, stream>>>(sbox, vbits, order,
                                                      keep_out);
  }
}

// Round 5
// 505.432 us; speedup vs baseline: 1.2926x; 1.0721x over previous
//
#include <hip/hip_runtime.h>

// Problem constants (fixed by reference): B=2, N=8192, C=80
constexpr int NB = 2;
constexpr int NN = 8192;
constexpr int NC = 80;
constexpr int ROWS = NN + 1;  // mask rows per batch; row NN is an all-zero row

// d_out layout (floats), in reference return order:
// boxes[B,N,4], max_scores[B,N], labels[B,N], keep[B,N], all_scores[B,N,C]
constexpr size_t OFF_BOXES  = 0;
constexpr size_t OFF_SCORES = (size_t)NB * NN * 4;
constexpr size_t OFF_LABELS = OFF_SCORES + (size_t)NB * NN;
constexpr size_t OFF_KEEP   = OFF_LABELS + (size_t)NB * NN;
constexpr size_t OFF_ALL    = OFF_KEEP + (size_t)NB * NN;

// d_ws layout
constexpr size_t WS_KEYS  = 0;                                   // B*N u64
constexpr size_t WS_VBYTE = WS_KEYS + (size_t)NB * NN * 8;       // B*N u8
constexpr size_t WS_ORDER = WS_VBYTE + (size_t)NB * NN;          // B*N i32
constexpr size_t WS_SBOX  = WS_ORDER + (size_t)NB * NN * 4;      // B*N float4
constexpr size_t WS_VBITS = WS_SBOX + (size_t)NB * NN * 16;      // B*128 u64
constexpr size_t WS_MASK  = WS_VBITS + (size_t)NB * 128 * 8;     // B*ROWS*128 u64
constexpr size_t WS_TOTAL = WS_MASK + (size_t)NB * ROWS * 128 * 8;

typedef unsigned long long u64;

// lgkmcnt(0)-only barrier: keeps global loads in flight across it.
// simm16: vmcnt[3:0]=0xF, expcnt=7<<4, lgkmcnt=0<<8, vmcnt[5:4]=3<<14 -> 0xC07F
__device__ inline void lbar() {
  __builtin_amdgcn_s_waitcnt(0xc07f);
  __builtin_amdgcn_s_barrier();
}

__device__ inline u64 readlane64(u64 v, int src) {
  unsigned int lo = (unsigned int)__builtin_amdgcn_readlane((int)(unsigned int)v, src);
  unsigned int hi = (unsigned int)__builtin_amdgcn_readlane((int)(unsigned int)(v >> 32), src);
  return ((u64)hi << 32) | lo;
}

__device__ inline u64 readfirstlane64(u64 v) {
  unsigned int lo = (unsigned int)__builtin_amdgcn_readfirstlane((int)(unsigned int)v);
  unsigned int hi = (unsigned int)__builtin_amdgcn_readfirstlane((int)(unsigned int)(v >> 32));
  return ((u64)hi << 32) | lo;
}

// IoU exactly mirroring the numpy op order; contraction off so f32 rounding
// matches numpy bit-for-bit (keep bits tolerate no error).
__device__ inline float iou_pair(const float4 p, const float4 q) {
#pragma clang fp contract(off)
  float areaA = (p.z - p.x) * (p.w - p.y);
  float areaB = (q.z - q.x) * (q.w - q.y);
  float ix1 = fmaxf(p.x, q.x);
  float iy1 = fmaxf(p.y, q.y);
  float ix2 = fminf(p.z, q.z);
  float iy2 = fminf(p.w, q.w);
  float inter = fmaxf(ix2 - ix1, 0.0f) * fmaxf(iy2 - iy1, 0.0f);
  float uni = areaA + areaB - inter;
  return inter / fmaxf(uni, 1e-9f);
}

__device__ inline float clip01(float v) { return fminf(fmaxf(v, 0.0f), 1.0f); }

// One wave per (b,n): sigmoid all 80 classes, max/argmax (first-index ties),
// box decode, validity, sort key. Also zero-inits vbits (scattered into by
// rank_kernel's atomicOr).
__global__ __launch_bounds__(256) void decode_kernel(
    const float* __restrict__ logits, const float4* __restrict__ deltas,
    const float4* __restrict__ anchors, float4* __restrict__ boxes_out,
    float* __restrict__ scores_out, float* __restrict__ labels_out,
    float* __restrict__ all_out, u64* __restrict__ keys,
    unsigned char* __restrict__ vbyte, u64* __restrict__ vbits) {
#pragma clang fp contract(off)
  if (blockIdx.x == 0 && threadIdx.x < NB * 128) vbits[threadIdx.x] = 0ull;
  int wid = (blockIdx.x * 256 + threadIdx.x) >> 6;  // 0 .. B*N-1
  int lane = threadIdx.x & 63;
  int n = wid & (NN - 1);
  size_t base = (size_t)wid * NC;

  float x0 = logits[base + lane];
  float sig0 = 1.0f / (1.0f + expf(-x0));
  all_out[base + lane] = sig0;
  float bs = sig0;
  int bidx = lane;
  if (lane < NC - 64) {
    float x1 = logits[base + 64 + lane];
    float sig1 = 1.0f / (1.0f + expf(-x1));
    all_out[base + 64 + lane] = sig1;
    if (sig1 > bs) { bs = sig1; bidx = lane + 64; }  // tie -> smaller idx wins
  }
  for (int off = 32; off; off >>= 1) {
    float os = __shfl_xor(bs, off, 64);
    int oi = __shfl_xor(bidx, off, 64);
    if (os > bs || (os == bs && oi < bidx)) { bs = os; bidx = oi; }
  }
  if (lane == 0) {
    float4 d = deltas[wid];
    float4 a = anchors[n];
    float aw = a.z - a.x, ah = a.w - a.y;
    float acx = a.x + 0.5f * aw, acy = a.y + 0.5f * ah;
    float dw = fminf(d.z, 4.0f), dh = fminf(d.w, 4.0f);
    float pcx = d.x * aw + acx;
    float pcy = d.y * ah + acy;
    float pw = expf(dw) * aw;
    float ph = expf(dh) * ah;
    float4 bx;
    bx.x = clip01(pcx - 0.5f * pw);
    bx.y = clip01(pcy - 0.5f * ph);
    bx.z = clip01(pcx + 0.5f * pw);
    bx.w = clip01(pcy + 0.5f * ph);
    boxes_out[wid] = bx;
    scores_out[wid] = bs;
    labels_out[wid] = (float)bidx;
    float bw = bx.z - bx.x, bh = bx.w - bx.y;
    bool valid = (bs > 0.5f) && (bw > 0.01f) && (bh > 0.01f) &&
                 (bw < 0.99f) && (bh < 0.99f);
    vbyte[wid] = valid ? 1 : 0;
    // score bits monotone (score>0); tie-break: smaller n first under
    // DESCENDING key sort -> (N-1-n) in low bits. Keys are UNIQUE.
    keys[wid] = ((u64)__float_as_uint(bs) << 32) | (unsigned int)(NN - 1 - n);
  }
}

// Rank sort: rank_i = #{j: key_j > key_i} (keys unique -> permutation).
// Block = 1024 threads = 256 rows x 4 column-quarters; column index is
// wave-uniform -> key loads scalarize.
__global__ __launch_bounds__(1024) void rank_kernel(
    const u64* __restrict__ keys, const float4* __restrict__ boxes,
    const unsigned char* __restrict__ vbyte, int* __restrict__ order,
    float4* __restrict__ sbox, u64* __restrict__ vbits) {
  int b = blockIdx.y;
  int r = threadIdx.x & 255;   // row slot
  int q = threadIdx.x >> 8;    // column quarter 0..3
  int i = blockIdx.x * 256 + r;
  const u64* kb = keys + (size_t)b * NN;
  u64 myk = kb[i];
  int cnt = 0;
  int j0 = q * (NN / 4), j1 = j0 + NN / 4;
#pragma unroll 8
  for (int j = j0; j < j1; ++j) {
    u64 kj = kb[j];  // wave-uniform address -> scalar load
    cnt += (kj > myk) ? 1 : 0;
  }
  __shared__ unsigned short part[4][256];
  part[q][r] = (unsigned short)cnt;
  __syncthreads();
  if (threadIdx.x < 256) {
    int rank = part[0][r] + part[1][r] + part[2][r] + part[3][r];
    order[(size_t)b * NN + rank] = i;
    sbox[(size_t)b * NN + rank] = boxes[(size_t)b * NN + i];
    if (vbyte[(size_t)b * NN + i])
      atomicOr(&vbits[b * 128 + (rank >> 6)], 1ull << (rank & 63));
  }
}

// 64x64 tile of the (sorted-order) suppression matrix: bit j set in row i's
// word iff j>i and IoU>0.5. Upper triangle only. Row stride padded: ROWS.
__global__ __launch_bounds__(64) void build_kernel(
    const float4* __restrict__ sbox, u64* __restrict__ mask) {
  int bx = blockIdx.x, by = blockIdx.y, b = blockIdx.z;
  if (bx < by) return;
  int lane = threadIdx.x;
  __shared__ float4 cb[64];
  cb[lane] = sbox[(size_t)b * NN + bx * 64 + lane];
  __syncthreads();
  int i = by * 64 + lane;
  float4 rb = sbox[(size_t)b * NN + i];
  u64 word = 0;
  int j0 = (bx == by) ? lane + 1 : 0;
  for (int jj = j0; jj < 64; ++jj)
    if (iou_pair(rb, cb[jj]) > 0.5f) word |= 1ull << jj;
  mask[((size_t)b * ROWS + i) * 128 + bx] = word;
}

// Greedy reduce v5: one 1024-thread block per batch, one lgkm-only barrier
// per chunk.
//  - Wave 0 ONLY runs the serial part: scalar (SALU) greedy bit-loop
//    (readfirstlane'd cand, readlane broadcasts of the prefetched diag word),
//    vbits held in wave-0 registers, parity-slot prefetch (load issued at
//    chunk c first read at c+2 -> >=1 full chunk of waitcnt slack).
//  - Waves 1..15: background row-OR. At chunk c ISSUE fixed-trip loads
//    (5 row-slots x ulonglong2, rowlist padded with the zero row NN) of
//    rowlist[c-1]'s mask words; CONSUME at c+1 into words > c+1.
//    Coverage: wave0 deposits words k+1,k+2 of chunk-k kept rows directly;
//    background covers words >= k+3. Word w is final before chunk w reads it.
__global__ __launch_bounds__(1024) void reduce_kernel(
    u64* __restrict__ mask, const u64* __restrict__ vbits,
    const int* __restrict__ order, float* __restrict__ keep_out) {
  int b = blockIdx.x, tid = threadIdx.x;
  int lane = tid & 63, wave = tid >> 6;
  __shared__ u64 s_remv[128];
  __shared__ u64 s_keep[128];
  __shared__ int s_rowlist[2][80];
  __shared__ int s_nk[2];
  u64* mbz = mask + (size_t)b * ROWS * 128;
  const u64* mb = mbz;

  for (int w = tid; w < 128; w += 1024) {
    s_remv[w] = 0ull;
    mbz[(size_t)NN * 128 + w] = 0ull;  // zero row (padded rowlist target)
  }
  if (tid < 2) s_nk[tid] = 0;
  if (tid < 160) s_rowlist[tid / 80][tid % 80] = NN;

  // Wave 0 registers: vbits words 2*lane, 2*lane+1; parity prefetch slots
  // (slot p holds chunk c with c&1==p: diag word c, next words c+1, c+2).
  u64 va = 0, vbb = 0;
  u64 pd[2] = {0, 0}, pn[2] = {0, 0}, pm[2] = {0, 0};
  if (wave == 0) {
    va = vbits[b * 128 + 2 * lane];
    vbb = vbits[b * 128 + 2 * lane + 1];
    const u64* r0 = mb + (size_t)lane * 128;
    pd[0] = r0[0]; pn[0] = r0[1]; pm[0] = r0[2];
    const u64* r1 = mb + (size_t)(64 + lane) * 128;
    pd[1] = r1[1]; pn[1] = r1[2]; pm[1] = r1[3];
  }
  // Background pipeline registers (5 row-slots x 2 words)
  u64 t0x = 0, t0y = 0, t1x = 0, t1y = 0, t2x = 0, t2y = 0, t3x = 0, t3y = 0,
      t4x = 0, t4y = 0;
  int w0i = 2 * lane, w1i = 2 * lane + 1;
  __syncthreads();  // full barrier: zero-row global write + LDS init visible

  for (int c = 0; c < 128; ++c) {
    if (wave == 0) {
      // ---- serial greedy for chunk c (scalar loop) ----
      int par = c & 1;
      u64 dA = pd[par], nA = pn[par], mA = pm[par];
      u64 rm = s_remv[c];                         // LDS broadcast read
      u64 vbw = readlane64(par ? vbb : va, c >> 1);
      u64 cand = readfirstlane64(vbw & ~rm);      // -> SALU loop below
      u64 kept = 0;
      while (cand) {
        int bi = (int)__builtin_ctzll(cand);
        u64 rd = readlane64(dA, bi);
        kept |= 1ull << bi;
        cand = (cand - 1) & cand & ~rd;
      }
      bool isk = (kept >> lane) & 1;
      if (c + 1 < 128 && isk && nA) atomicOr(&s_remv[c + 1], nA);
      if (c + 2 < 128 && isk && mA) atomicOr(&s_remv[c + 2], mA);
      s_rowlist[par][lane] = NN;  // pad; kept positions overwrite below
      if (isk) {
        int pos = __popcll(kept & ((1ull << lane) - 1ull));
        s_rowlist[par][pos] = c * 64 + lane;
      }
      if (lane == 0) {
        s_keep[c] = kept;
        s_nk[par] = __popcll(kept);
      }
      // ---- prefetch chunk c+2 into this parity slot (read at c+2) ----
      if (c + 2 < 128) {
        const u64* rp = mb + (size_t)((c + 2) * 64 + lane) * 128;
        pd[par] = rp[c + 2];
        pn[par] = (c + 3 < 128) ? rp[c + 3] : 0;
        pm[par] = (c + 4 < 128) ? rp[c + 4] : 0;
      }
    } else {
      // ---- background: consume rows of chunk c-2 into words > c ----
      u64 ax = t0x | t1x | t2x | t3x | t4x;
      u64 ay = t0y | t1y | t2y | t3y | t4y;
      if (w0i > c && ax) atomicOr(&s_remv[w0i], ax);
      if (w1i > c && ay) atomicOr(&s_remv[w1i], ay);
      // ---- issue loads for rows of chunk c-1 (consumed at c+1) ----
      int nk1 = s_nk[(c - 1) & 1];  // c=0 -> slot 1 = 0
      t0x = t0y = t1x = t1y = t2x = t2y = t3x = t3y = t4x = t4y = 0;
      if (nk1 > 0 && w1i > c + 1) {
        const int* rl = s_rowlist[(c - 1) & 1];
        int r0 = rl[wave - 1], r1 = rl[wave + 14], r2 = rl[wave + 29],
            r3 = rl[wave + 44], r4 = rl[wave + 59];
        ulonglong2 v0 = *(const ulonglong2*)(mb + (size_t)r0 * 128 + w0i);
        ulonglong2 v1 = *(const ulonglong2*)(mb + (size_t)r1 * 128 + w0i);
        ulonglong2 v2 = *(const ulonglong2*)(mb + (size_t)r2 * 128 + w0i);
        ulonglong2 v3 = *(const ulonglong2*)(mb + (size_t)r3 * 128 + w0i);
        ulonglong2 v4 = *(const ulonglong2*)(mb + (size_t)r4 * 128 + w0i);
        t0x = v0.x; t0y = v0.y; t1x = v1.x; t1y = v1.y;
        t2x = v2.x; t2y = v2.y; t3x = v3.x; t3y = v3.y;
        t4x = v4.x; t4y = v4.y;
      }
    }
    lbar();  // lgkm-only: LDS ordered, global loads stay in flight
  }

  // scatter keep flags back to original anchor order
  for (int p = tid; p < NN; p += 1024) {
    int orig = order[(size_t)b * NN + p];
    keep_out[(size_t)b * NN + orig] =
        ((s_keep[p >> 6] >> (p & 63)) & 1) ? 1.0f : 0.0f;
  }
}

// Slow-but-correct fallback if d_ws can't hold the mask: classic iterative
// greedy NMS, one block per batch.
__global__ __launch_bounds__(1024) void nms_fallback(
    const float4* __restrict__ sbox, const u64* __restrict__ vbits,
    const int* __restrict__ order, float* __restrict__ keep_out) {
  int b = blockIdx.x, tid = threadIdx.x;
  __shared__ u64 dead[128];
  __shared__ int s_next;
  __shared__ float4 s_box;
  for (int w = tid; w < 128; w += 1024) dead[w] = ~vbits[b * 128 + w];
  for (int p = tid; p < NN; p += 1024)
    keep_out[(size_t)b * NN + order[(size_t)b * NN + p]] = 0.0f;
  __syncthreads();
  int i = 0;
  while (true) {
    if (tid == 0) {
      int nxt = NN;
      int w = i >> 6;
      u64 live = ~dead[w] & (~0ull << (i & 63));
      while (true) {
        if (live) { nxt = w * 64 + __builtin_ctzll(live); break; }
        if (++w >= 128) break;
        live = ~dead[w];
      }
      s_next = nxt;
      if (nxt < NN) {
        s_box = sbox[(size_t)b * NN + nxt];
        keep_out[(size_t)b * NN + order[(size_t)b * NN + nxt]] = 1.0f;
      }
    }
    __syncthreads();
    i = s_next;
    if (i >= NN) break;
    float4 kb = s_box;
    for (int j = i + 1 + tid; j < NN; j += 1024) {
      if (iou_pair(kb, sbox[(size_t)b * NN + j]) > 0.5f)
        atomicOr(&dead[j >> 6], 1ull << (j & 63));
    }
    __syncthreads();
    i = i + 1;
  }
}

extern "C" void kernel_launch(void* const* d_in, const int* in_sizes, int n_in,
                              void* d_out, int out_size, void* d_ws, size_t ws_size,
                              hipStream_t stream) {
  const float* logits = (const float*)d_in[0];
  const float4* deltas = (const float4*)d_in[1];
  const float4* anchors = (const float4*)d_in[2];
  float* out = (float*)d_out;
  float4* boxes_out = (float4*)(out + OFF_BOXES);
  float* scores_out = out + OFF_SCORES;
  float* labels_out = out + OFF_LABELS;
  float* keep_out = out + OFF_KEEP;
  float* all_out = out + OFF_ALL;

  char* ws = (char*)d_ws;
  u64* keys = (u64*)(ws + WS_KEYS);
  unsigned char* vbyte = (unsigned char*)(ws + WS_VBYTE);
  int* order = (int*)(ws + WS_ORDER);
  float4* sbox = (float4*)(ws + WS_SBOX);
  u64* vbits = (u64*)(ws + WS_VBITS);
  u64* mask = (u64*)(ws + WS_MASK);

  decode_kernel<<<dim3(NB * NN / 4), dim3(256), 0, stream>>>(
      logits, deltas, anchors, boxes_out, scores_out, labels_out, all_out,
      keys, vbyte, vbits);
  rank_kernel<<<dim3(NN / 256, NB), dim3(1024), 0, stream>>>(
      keys, (const float4*)boxes_out, vbyte, order, sbox, vbits);
  if (ws_size >= WS_TOTAL) {
    build_kernel<<<dim3(128, 128, NB), dim3(64), 0, stream>>>(sbox, mask);
    reduce_kernel<<<dim3(NB), dim3(1024), 0, stream>>>(mask, vbits, order,
                                                       keep_out);
  } else {
    nms_fallback<<<dim3(NB), dim3(1024), 0, stream>>>(sbox, vbits, order,
                                                      keep_out);
  }
}

// Round 6
// 449.326 us; speedup vs baseline: 1.4541x; 1.1249x over previous
//
#include <hip/hip_runtime.h>

// Problem constants (fixed by reference): B=2, N=8192, C=80
constexpr int NB = 2;
constexpr int NN = 8192;
constexpr int NC = 80;
constexpr int ROWS = NN + 1;  // mask rows per batch; row NN is an all-zero row

// d_out layout (floats), in reference return order:
// boxes[B,N,4], max_scores[B,N], labels[B,N], keep[B,N], all_scores[B,N,C]
constexpr size_t OFF_BOXES  = 0;
constexpr size_t OFF_SCORES = (size_t)NB * NN * 4;
constexpr size_t OFF_LABELS = OFF_SCORES + (size_t)NB * NN;
constexpr size_t OFF_KEEP   = OFF_LABELS + (size_t)NB * NN;
constexpr size_t OFF_ALL    = OFF_KEEP + (size_t)NB * NN;

// d_ws layout
constexpr size_t WS_KEYS  = 0;                                   // B*N u64
constexpr size_t WS_VBYTE = WS_KEYS + (size_t)NB * NN * 8;       // B*N u8
constexpr size_t WS_ORDER = WS_VBYTE + (size_t)NB * NN;          // B*N i32
constexpr size_t WS_SBOX  = WS_ORDER + (size_t)NB * NN * 4;      // B*N float4
constexpr size_t WS_VBITS = WS_SBOX + (size_t)NB * NN * 16;      // B*128 u64
constexpr size_t WS_MASK  = WS_VBITS + (size_t)NB * 128 * 8;     // B*ROWS*128 u64
constexpr size_t WS_DNM   = WS_MASK + (size_t)NB * ROWS * 128 * 8; // B*128*3*64 u64
constexpr size_t WS_TOTAL = WS_DNM + (size_t)NB * 128 * 3 * 64 * 8;
constexpr int DNM_WORDS = NB * 128 * 3 * 64;  // 98304

typedef unsigned long long u64;

// lgkmcnt(0)-only barrier: keeps global loads in flight across it.
// simm16: vmcnt[3:0]=0xF, expcnt=7<<4, lgkmcnt=0<<8, vmcnt[5:4]=3<<14 -> 0xC07F
__device__ inline void lbar() {
  __builtin_amdgcn_s_waitcnt(0xc07f);
  __builtin_amdgcn_s_barrier();
}

__device__ inline u64 readlane64(u64 v, int src) {
  unsigned int lo = (unsigned int)__builtin_amdgcn_readlane((int)(unsigned int)v, src);
  unsigned int hi = (unsigned int)__builtin_amdgcn_readlane((int)(unsigned int)(v >> 32), src);
  return ((u64)hi << 32) | lo;
}

__device__ inline u64 readfirstlane64(u64 v) {
  unsigned int lo = (unsigned int)__builtin_amdgcn_readfirstlane((int)(unsigned int)v);
  unsigned int hi = (unsigned int)__builtin_amdgcn_readfirstlane((int)(unsigned int)(v >> 32));
  return ((u64)hi << 32) | lo;
}

// IoU exactly mirroring the numpy op order; contraction off so f32 rounding
// matches numpy bit-for-bit (keep bits tolerate no error).
__device__ inline float iou_pair(const float4 p, const float4 q) {
#pragma clang fp contract(off)
  float areaA = (p.z - p.x) * (p.w - p.y);
  float areaB = (q.z - q.x) * (q.w - q.y);
  float ix1 = fmaxf(p.x, q.x);
  float iy1 = fmaxf(p.y, q.y);
  float ix2 = fminf(p.z, q.z);
  float iy2 = fminf(p.w, q.w);
  float inter = fmaxf(ix2 - ix1, 0.0f) * fmaxf(iy2 - iy1, 0.0f);
  float uni = areaA + areaB - inter;
  return inter / fmaxf(uni, 1e-9f);
}

__device__ inline float clip01(float v) { return fminf(fmaxf(v, 0.0f), 1.0f); }

// One wave per (b,n): sigmoid all 80 classes, max/argmax (first-index ties),
// box decode, validity, sort key. Also zero-inits vbits.
__global__ __launch_bounds__(256) void decode_kernel(
    const float* __restrict__ logits, const float4* __restrict__ deltas,
    const float4* __restrict__ anchors, float4* __restrict__ boxes_out,
    float* __restrict__ scores_out, float* __restrict__ labels_out,
    float* __restrict__ all_out, u64* __restrict__ keys,
    unsigned char* __restrict__ vbyte, u64* __restrict__ vbits) {
#pragma clang fp contract(off)
  if (blockIdx.x == 0 && threadIdx.x < NB * 128) vbits[threadIdx.x] = 0ull;
  int wid = (blockIdx.x * 256 + threadIdx.x) >> 6;  // 0 .. B*N-1
  int lane = threadIdx.x & 63;
  int n = wid & (NN - 1);
  size_t base = (size_t)wid * NC;

  float x0 = logits[base + lane];
  float sig0 = 1.0f / (1.0f + expf(-x0));
  all_out[base + lane] = sig0;
  float bs = sig0;
  int bidx = lane;
  if (lane < NC - 64) {
    float x1 = logits[base + 64 + lane];
    float sig1 = 1.0f / (1.0f + expf(-x1));
    all_out[base + 64 + lane] = sig1;
    if (sig1 > bs) { bs = sig1; bidx = lane + 64; }  // tie -> smaller idx wins
  }
  for (int off = 32; off; off >>= 1) {
    float os = __shfl_xor(bs, off, 64);
    int oi = __shfl_xor(bidx, off, 64);
    if (os > bs || (os == bs && oi < bidx)) { bs = os; bidx = oi; }
  }
  if (lane == 0) {
    float4 d = deltas[wid];
    float4 a = anchors[n];
    float aw = a.z - a.x, ah = a.w - a.y;
    float acx = a.x + 0.5f * aw, acy = a.y + 0.5f * ah;
    float dw = fminf(d.z, 4.0f), dh = fminf(d.w, 4.0f);
    float pcx = d.x * aw + acx;
    float pcy = d.y * ah + acy;
    float pw = expf(dw) * aw;
    float ph = expf(dh) * ah;
    float4 bx;
    bx.x = clip01(pcx - 0.5f * pw);
    bx.y = clip01(pcy - 0.5f * ph);
    bx.z = clip01(pcx + 0.5f * pw);
    bx.w = clip01(pcy + 0.5f * ph);
    boxes_out[wid] = bx;
    scores_out[wid] = bs;
    labels_out[wid] = (float)bidx;
    float bw = bx.z - bx.x, bh = bx.w - bx.y;
    bool valid = (bs > 0.5f) && (bw > 0.01f) && (bh > 0.01f) &&
                 (bw < 0.99f) && (bh < 0.99f);
    vbyte[wid] = valid ? 1 : 0;
    // score bits monotone (score>0); tie-break: smaller n first under
    // DESCENDING key sort -> (N-1-n) in low bits. Keys are UNIQUE.
    keys[wid] = ((u64)__float_as_uint(bs) << 32) | (unsigned int)(NN - 1 - n);
  }
}

// Rank sort: rank_i = #{j: key_j > key_i} (keys unique -> permutation).
// Block = 1024 threads = 256 rows x 4 column-quarters; column index is
// wave-uniform -> key loads scalarize. Also zero-inits dnm (written by
// build_kernel, which runs after this on the stream).
__global__ __launch_bounds__(1024) void rank_kernel(
    const u64* __restrict__ keys, const float4* __restrict__ boxes,
    const unsigned char* __restrict__ vbyte, int* __restrict__ order,
    float4* __restrict__ sbox, u64* __restrict__ vbits,
    u64* __restrict__ dnm) {
  int b = blockIdx.y;
  int gid = (blockIdx.y * gridDim.x + blockIdx.x) * 1024 + threadIdx.x;
  for (int z = gid; z < DNM_WORDS; z += 65536) dnm[z] = 0ull;
  int r = threadIdx.x & 255;   // row slot
  int q = threadIdx.x >> 8;    // column quarter 0..3
  int i = blockIdx.x * 256 + r;
  const u64* kb = keys + (size_t)b * NN;
  u64 myk = kb[i];
  int cnt = 0;
  int j0 = q * (NN / 4), j1 = j0 + NN / 4;
#pragma unroll 8
  for (int j = j0; j < j1; ++j) {
    u64 kj = kb[j];  // wave-uniform address -> scalar load
    cnt += (kj > myk) ? 1 : 0;
  }
  __shared__ unsigned short part[4][256];
  part[q][r] = (unsigned short)cnt;
  __syncthreads();
  if (threadIdx.x < 256) {
    int rank = part[0][r] + part[1][r] + part[2][r] + part[3][r];
    order[(size_t)b * NN + rank] = i;
    sbox[(size_t)b * NN + rank] = boxes[(size_t)b * NN + i];
    if (vbyte[(size_t)b * NN + i])
      atomicOr(&vbits[b * 128 + (rank >> 6)], 1ull << (rank & 63));
  }
}

// 64x64 tile of the (sorted-order) suppression matrix: bit j set in row i's
// word iff j>i and IoU>0.5. Upper triangle only. Tiles on/near the diagonal
// (bx-by in {0,1,2}) also write the COMPACT dnm array so reduce's wave 0 can
// prefetch with coalesced 512B loads instead of a 64-cacheline gather.
__global__ __launch_bounds__(64) void build_kernel(
    const float4* __restrict__ sbox, u64* __restrict__ mask,
    u64* __restrict__ dnm) {
  int bx = blockIdx.x, by = blockIdx.y, b = blockIdx.z;
  if (bx < by) return;
  int lane = threadIdx.x;
  __shared__ float4 cb[64];
  cb[lane] = sbox[(size_t)b * NN + bx * 64 + lane];
  __syncthreads();
  int i = by * 64 + lane;
  float4 rb = sbox[(size_t)b * NN + i];
  u64 word = 0;
  int j0 = (bx == by) ? lane + 1 : 0;
  for (int jj = j0; jj < 64; ++jj)
    if (iou_pair(rb, cb[jj]) > 0.5f) word |= 1ull << jj;
  mask[((size_t)b * ROWS + i) * 128 + bx] = word;
  int dq = bx - by;
  if (dq < 3) dnm[(((size_t)b * 128 + by) * 3 + dq) * 64 + lane] = word;
}

// Greedy reduce v6: one 512-thread block per batch (wave0 serial + 7
// background waves), one lgkm-only barrier per chunk.
//  - Wave 0 prefetches chunk c+2's diag/next/next2 words from the COMPACT
//    dnm array (coalesced 512B loads) directly into the (c+2)%4 register
//    slot of a 4x-unrolled loop -> no register copies / parity selects, so
//    the compiler's waitcnt before use only retires loads >= 2 chunks old.
//  - Serial greedy bit-loop is scalar (readfirstlane'd cand, readlane
//    broadcast of diag); kept lanes deposit words c+1, c+2 via LDS atomicOr.
//  - Background waves 1..7: at chunk c ISSUE fixed-trip coalesced loads
//    (10 row-slots x ulonglong2, rowlist padded with zero row NN) of
//    rowlist[c-1]'s mask words; CONSUME at c+1 into words > c+1.
//    Coverage: wave0 covers words k+1,k+2 of chunk-k kept rows; background
//    covers words >= k+3, landing at chunk k+2 < deadline.
__global__ __launch_bounds__(512) void reduce_kernel(
    u64* __restrict__ mask, const u64* __restrict__ vbits,
    const u64* __restrict__ dnm, const int* __restrict__ order,
    float* __restrict__ keep_out) {
  int b = blockIdx.x, tid = threadIdx.x;
  int lane = tid & 63, wave = tid >> 6;
  __shared__ u64 s_remv[128];
  __shared__ u64 s_keep[128];
  __shared__ int s_rowlist[2][80];
  __shared__ int s_nk[2];
  u64* mbz = mask + (size_t)b * ROWS * 128;
  const u64* mb = mbz;
  const u64* dn = dnm + (size_t)b * 128 * 3 * 64;

  for (int w = tid; w < 128; w += 512) {
    s_remv[w] = 0ull;
    mbz[(size_t)NN * 128 + w] = 0ull;  // zero row (padded rowlist target)
  }
  if (tid < 2) s_nk[tid] = 0;
  if (tid < 160) s_rowlist[tid / 80][tid % 80] = NN;

  // Wave 0 state: vbits in regs; 4 rotating prefetch slots (d,n,m each).
  u64 va = 0, vb2 = 0;
  u64 dA = 0, nA = 0, mA = 0, dB = 0, nB = 0, mB = 0;
  u64 dC = 0, nC = 0, mC = 0, dD = 0, nD = 0, mD = 0;
  if (wave == 0) {
    va = vbits[b * 128 + 2 * lane];
    vb2 = vbits[b * 128 + 2 * lane + 1];
    const u64* r0 = dn + lane;           // chunk 0
    dA = r0[0]; nA = r0[64]; mA = r0[128];
    const u64* r1 = dn + 3 * 64 + lane;  // chunk 1
    dB = r1[0]; nB = r1[64]; mB = r1[128];
  }
  // Background pipeline registers (10 row-slots x ulonglong2)
  ulonglong2 t0{}, t1{}, t2{}, t3{}, t4{}, t5{}, t6{}, t7{}, t8{}, t9{};
  int w0i = 2 * lane, w1i = 2 * lane + 1;
  __syncthreads();  // full barrier: zero-row global write + LDS init visible

  // Serial body for chunk c: use (dcur,ncur,mcur) slot; prefetch chunk c+2
  // into (dnew,nnew,mnew) slot (its previous value died at body c-2).
  auto serial_body = [&](int c, u64 dcur, u64 ncur, u64 mcur, u64& dnew,
                         u64& nnew, u64& mnew) {
    if (c + 2 < 128) {  // issue first, consume 2 chunks later
      const u64* rp = dn + (size_t)(c + 2) * 3 * 64 + lane;
      dnew = rp[0]; nnew = rp[64]; mnew = rp[128];
    } else {
      dnew = 0; nnew = 0; mnew = 0;
    }
    int par = c & 1;
    u64 rm = s_remv[c];  // LDS broadcast read
    u64 vbw = readlane64(par ? vb2 : va, c >> 1);
    u64 cand = readfirstlane64(vbw & ~rm);  // -> SALU loop
    u64 kept = 0;
    while (cand) {
      int bi = (int)__builtin_ctzll(cand);
      u64 rd = readlane64(dcur, bi);
      kept |= 1ull << bi;
      cand = (cand - 1) & cand & ~rd;
    }
    bool isk = (kept >> lane) & 1;
    if (c + 1 < 128 && isk && ncur) atomicOr(&s_remv[c + 1], ncur);
    if (c + 2 < 128 && isk && mcur) atomicOr(&s_remv[c + 2], mcur);
    s_rowlist[par][lane] = NN;  // pad; kept positions overwrite below
    if (isk) {
      int pos = __popcll(kept & ((1ull << lane) - 1ull));
      s_rowlist[par][pos] = c * 64 + lane;
    }
    if (lane == 0) {
      s_keep[c] = kept;
      s_nk[par] = __popcll(kept);
    }
  };

  auto bg_body = [&](int c) {
    // consume rows of chunk c-2 into words > c
    u64 ax = t0.x | t1.x | t2.x | t3.x | t4.x | t5.x | t6.x | t7.x | t8.x | t9.x;
    u64 ay = t0.y | t1.y | t2.y | t3.y | t4.y | t5.y | t6.y | t7.y | t8.y | t9.y;
    if (w0i > c && ax) atomicOr(&s_remv[w0i], ax);
    if (w1i > c && ay) atomicOr(&s_remv[w1i], ay);
    // issue loads for rows of chunk c-1 (consumed at c+1)
    int nk1 = s_nk[(c - 1) & 1];  // c=0 -> slot 1 = 0
    t0 = t1 = t2 = t3 = t4 = t5 = t6 = t7 = t8 = t9 = ulonglong2{0, 0};
    if (nk1 > 0 && w1i > c + 1) {
      const int* rl = s_rowlist[(c - 1) & 1];
      int base = wave - 1;
      int r0 = rl[base], r1 = rl[base + 7], r2 = rl[base + 14],
          r3 = rl[base + 21], r4 = rl[base + 28], r5 = rl[base + 35],
          r6 = rl[base + 42], r7 = rl[base + 49], r8 = rl[base + 56],
          r9 = rl[base + 63];
      t0 = *(const ulonglong2*)(mb + (size_t)r0 * 128 + w0i);
      t1 = *(const ulonglong2*)(mb + (size_t)r1 * 128 + w0i);
      t2 = *(const ulonglong2*)(mb + (size_t)r2 * 128 + w0i);
      t3 = *(const ulonglong2*)(mb + (size_t)r3 * 128 + w0i);
      t4 = *(const ulonglong2*)(mb + (size_t)r4 * 128 + w0i);
      t5 = *(const ulonglong2*)(mb + (size_t)r5 * 128 + w0i);
      t6 = *(const ulonglong2*)(mb + (size_t)r6 * 128 + w0i);
      t7 = *(const ulonglong2*)(mb + (size_t)r7 * 128 + w0i);
      t8 = *(const ulonglong2*)(mb + (size_t)r8 * 128 + w0i);
      t9 = *(const ulonglong2*)(mb + (size_t)r9 * 128 + w0i);
    }
  };

  for (int c = 0; c < 128; c += 4) {
    if (wave == 0) serial_body(c, dA, nA, mA, dC, nC, mC);
    else bg_body(c);
    lbar();
    if (wave == 0) serial_body(c + 1, dB, nB, mB, dD, nD, mD);
    else bg_body(c + 1);
    lbar();
    if (wave == 0) serial_body(c + 2, dC, nC, mC, dA, nA, mA);
    else bg_body(c + 2);
    lbar();
    if (wave == 0) serial_body(c + 3, dD, nD, mD, dB, nB, mB);
    else bg_body(c + 3);
    lbar();
  }

  // scatter keep flags back to original anchor order
  for (int p = tid; p < NN; p += 512) {
    int orig = order[(size_t)b * NN + p];
    keep_out[(size_t)b * NN + orig] =
        ((s_keep[p >> 6] >> (p & 63)) & 1) ? 1.0f : 0.0f;
  }
}

// Slow-but-correct fallback if d_ws can't hold the mask: classic iterative
// greedy NMS, one block per batch.
__global__ __launch_bounds__(1024) void nms_fallback(
    const float4* __restrict__ sbox, const u64* __restrict__ vbits,
    const int* __restrict__ order, float* __restrict__ keep_out) {
  int b = blockIdx.x, tid = threadIdx.x;
  __shared__ u64 dead[128];
  __shared__ int s_next;
  __shared__ float4 s_box;
  for (int w = tid; w < 128; w += 1024) dead[w] = ~vbits[b * 128 + w];
  for (int p = tid; p < NN; p += 1024)
    keep_out[(size_t)b * NN + order[(size_t)b * NN + p]] = 0.0f;
  __syncthreads();
  int i = 0;
  while (true) {
    if (tid == 0) {
      int nxt = NN;
      int w = i >> 6;
      u64 live = ~dead[w] & (~0ull << (i & 63));
      while (true) {
        if (live) { nxt = w * 64 + __builtin_ctzll(live); break; }
        if (++w >= 128) break;
        live = ~dead[w];
      }
      s_next = nxt;
      if (nxt < NN) {
        s_box = sbox[(size_t)b * NN + nxt];
        keep_out[(size_t)b * NN + order[(size_t)b * NN + nxt]] = 1.0f;
      }
    }
    __syncthreads();
    i = s_next;
    if (i >= NN) break;
    float4 kb = s_box;
    for (int j = i + 1 + tid; j < NN; j += 1024) {
      if (iou_pair(kb, sbox[(size_t)b * NN + j]) > 0.5f)
        atomicOr(&dead[j >> 6], 1ull << (j & 63));
    }
    __syncthreads();
    i = i + 1;
  }
}

extern "C" void kernel_launch(void* const* d_in, const int* in_sizes, int n_in,
                              void* d_out, int out_size, void* d_ws, size_t ws_size,
                              hipStream_t stream) {
  const float* logits = (const float*)d_in[0];
  const float4* deltas = (const float4*)d_in[1];
  const float4* anchors = (const float4*)d_in[2];
  float* out = (float*)d_out;
  float4* boxes_out = (float4*)(out + OFF_BOXES);
  float* scores_out = out + OFF_SCORES;
  float* labels_out = out + OFF_LABELS;
  float* keep_out = out + OFF_KEEP;
  float* all_out = out + OFF_ALL;

  char* ws = (char*)d_ws;
  u64* keys = (u64*)(ws + WS_KEYS);
  unsigned char* vbyte = (unsigned char*)(ws + WS_VBYTE);
  int* order = (int*)(ws + WS_ORDER);
  float4* sbox = (float4*)(ws + WS_SBOX);
  u64* vbits = (u64*)(ws + WS_VBITS);
  u64* mask = (u64*)(ws + WS_MASK);
  u64* dnm = (u64*)(ws + WS_DNM);

  decode_kernel<<<dim3(NB * NN / 4), dim3(256), 0, stream>>>(
      logits, deltas, anchors, boxes_out, scores_out, labels_out, all_out,
      keys, vbyte, vbits);
  rank_kernel<<<dim3(NN / 256, NB), dim3(1024), 0, stream>>>(
      keys, (const float4*)boxes_out, vbyte, order, sbox, vbits, dnm);
  if (ws_size >= WS_TOTAL) {
    build_kernel<<<dim3(128, 128, NB), dim3(64), 0, stream>>>(sbox, mask, dnm);
    reduce_kernel<<<dim3(NB), dim3(512), 0, stream>>>(mask, vbits, dnm, order,
                                                      keep_out);
  } else {
    nms_fallback<<<dim3(NB), dim3(1024), 0, stream>>>(sbox, vbits, order,
                                                      keep_out);
  }
}

// Round 7
// 448.761 us; speedup vs baseline: 1.4559x; 1.0013x over previous
//
#include <hip/hip_runtime.h>

// Problem constants (fixed by reference): B=2, N=8192, C=80
constexpr int NB = 2;
constexpr int NN = 8192;
constexpr int NC = 80;
constexpr int ROWS = NN + 1;  // mask rows per batch; row NN is an all-zero row

// d_out layout (floats), in reference return order:
// boxes[B,N,4], max_scores[B,N], labels[B,N], keep[B,N], all_scores[B,N,C]
constexpr size_t OFF_BOXES  = 0;
constexpr size_t OFF_SCORES = (size_t)NB * NN * 4;
constexpr size_t OFF_LABELS = OFF_SCORES + (size_t)NB * NN;
constexpr size_t OFF_KEEP   = OFF_LABELS + (size_t)NB * NN;
constexpr size_t OFF_ALL    = OFF_KEEP + (size_t)NB * NN;

// d_ws layout
constexpr size_t WS_KEYS  = 0;                                   // B*N u64
constexpr size_t WS_VBYTE = WS_KEYS + (size_t)NB * NN * 8;       // B*N u8
constexpr size_t WS_ORDER = WS_VBYTE + (size_t)NB * NN;          // B*N i32
constexpr size_t WS_SBOX  = WS_ORDER + (size_t)NB * NN * 4;      // B*N float4
constexpr size_t WS_VBITS = WS_SBOX + (size_t)NB * NN * 16;      // B*128 u64
constexpr size_t WS_MASK  = WS_VBITS + (size_t)NB * 128 * 8;     // B*ROWS*128 u64
constexpr size_t WS_DNM   = WS_MASK + (size_t)NB * ROWS * 128 * 8; // B*128*4*64 u64
constexpr size_t WS_TOTAL = WS_DNM + (size_t)NB * 128 * 4 * 64 * 8;
constexpr int DNM_WORDS = NB * 128 * 4 * 64;  // 65536

typedef unsigned long long u64;

// lgkmcnt(0)-only barrier: keeps global loads in flight across it.
// simm16: vmcnt[3:0]=0xF, expcnt=7<<4, lgkmcnt=0<<8, vmcnt[5:4]=3<<14 -> 0xC07F
__device__ inline void lbar() {
  __builtin_amdgcn_s_waitcnt(0xc07f);
  __builtin_amdgcn_s_barrier();
}

__device__ inline u64 readlane64(u64 v, int src) {
  unsigned int lo = (unsigned int)__builtin_amdgcn_readlane((int)(unsigned int)v, src);
  unsigned int hi = (unsigned int)__builtin_amdgcn_readlane((int)(unsigned int)(v >> 32), src);
  return ((u64)hi << 32) | lo;
}

__device__ inline u64 readfirstlane64(u64 v) {
  unsigned int lo = (unsigned int)__builtin_amdgcn_readfirstlane((int)(unsigned int)v);
  unsigned int hi = (unsigned int)__builtin_amdgcn_readfirstlane((int)(unsigned int)(v >> 32));
  return ((u64)hi << 32) | lo;
}

// IoU exactly mirroring the numpy op order; contraction off so f32 rounding
// matches numpy bit-for-bit (keep bits tolerate no error).
__device__ inline float iou_pair(const float4 p, const float4 q) {
#pragma clang fp contract(off)
  float areaA = (p.z - p.x) * (p.w - p.y);
  float areaB = (q.z - q.x) * (q.w - q.y);
  float ix1 = fmaxf(p.x, q.x);
  float iy1 = fmaxf(p.y, q.y);
  float ix2 = fminf(p.z, q.z);
  float iy2 = fminf(p.w, q.w);
  float inter = fmaxf(ix2 - ix1, 0.0f) * fmaxf(iy2 - iy1, 0.0f);
  float uni = areaA + areaB - inter;
  return inter / fmaxf(uni, 1e-9f);
}

__device__ inline float clip01(float v) { return fminf(fmaxf(v, 0.0f), 1.0f); }

// One wave per (b,n): sigmoid all 80 classes, max/argmax (first-index ties),
// box decode, validity, sort key. Also zero-inits vbits.
__global__ __launch_bounds__(256) void decode_kernel(
    const float* __restrict__ logits, const float4* __restrict__ deltas,
    const float4* __restrict__ anchors, float4* __restrict__ boxes_out,
    float* __restrict__ scores_out, float* __restrict__ labels_out,
    float* __restrict__ all_out, u64* __restrict__ keys,
    unsigned char* __restrict__ vbyte, u64* __restrict__ vbits) {
#pragma clang fp contract(off)
  if (blockIdx.x == 0 && threadIdx.x < NB * 128) vbits[threadIdx.x] = 0ull;
  int wid = (blockIdx.x * 256 + threadIdx.x) >> 6;  // 0 .. B*N-1
  int lane = threadIdx.x & 63;
  int n = wid & (NN - 1);
  size_t base = (size_t)wid * NC;

  float x0 = logits[base + lane];
  float sig0 = 1.0f / (1.0f + expf(-x0));
  all_out[base + lane] = sig0;
  float bs = sig0;
  int bidx = lane;
  if (lane < NC - 64) {
    float x1 = logits[base + 64 + lane];
    float sig1 = 1.0f / (1.0f + expf(-x1));
    all_out[base + 64 + lane] = sig1;
    if (sig1 > bs) { bs = sig1; bidx = lane + 64; }  // tie -> smaller idx wins
  }
  for (int off = 32; off; off >>= 1) {
    float os = __shfl_xor(bs, off, 64);
    int oi = __shfl_xor(bidx, off, 64);
    if (os > bs || (os == bs && oi < bidx)) { bs = os; bidx = oi; }
  }
  if (lane == 0) {
    float4 d = deltas[wid];
    float4 a = anchors[n];
    float aw = a.z - a.x, ah = a.w - a.y;
    float acx = a.x + 0.5f * aw, acy = a.y + 0.5f * ah;
    float dw = fminf(d.z, 4.0f), dh = fminf(d.w, 4.0f);
    float pcx = d.x * aw + acx;
    float pcy = d.y * ah + acy;
    float pw = expf(dw) * aw;
    float ph = expf(dh) * ah;
    float4 bx;
    bx.x = clip01(pcx - 0.5f * pw);
    bx.y = clip01(pcy - 0.5f * ph);
    bx.z = clip01(pcx + 0.5f * pw);
    bx.w = clip01(pcy + 0.5f * ph);
    boxes_out[wid] = bx;
    scores_out[wid] = bs;
    labels_out[wid] = (float)bidx;
    float bw = bx.z - bx.x, bh = bx.w - bx.y;
    bool valid = (bs > 0.5f) && (bw > 0.01f) && (bh > 0.01f) &&
                 (bw < 0.99f) && (bh < 0.99f);
    vbyte[wid] = valid ? 1 : 0;
    // score bits monotone (score>0); tie-break: smaller n first under
    // DESCENDING key sort -> (N-1-n) in low bits. Keys are UNIQUE.
    keys[wid] = ((u64)__float_as_uint(bs) << 32) | (unsigned int)(NN - 1 - n);
  }
}

// Rank sort: rank_i = #{j: key_j > key_i} (keys unique -> permutation).
// Block = 1024 threads = 256 rows x 4 column-quarters; column index is
// wave-uniform -> key loads scalarize. Also zero-inits dnm.
__global__ __launch_bounds__(1024) void rank_kernel(
    const u64* __restrict__ keys, const float4* __restrict__ boxes,
    const unsigned char* __restrict__ vbyte, int* __restrict__ order,
    float4* __restrict__ sbox, u64* __restrict__ vbits,
    u64* __restrict__ dnm) {
  int b = blockIdx.y;
  int gid = (blockIdx.y * gridDim.x + blockIdx.x) * 1024 + threadIdx.x;
  for (int z = gid; z < DNM_WORDS; z += 65536) dnm[z] = 0ull;
  int r = threadIdx.x & 255;   // row slot
  int q = threadIdx.x >> 8;    // column quarter 0..3
  int i = blockIdx.x * 256 + r;
  const u64* kb = keys + (size_t)b * NN;
  u64 myk = kb[i];
  int cnt = 0;
  int j0 = q * (NN / 4), j1 = j0 + NN / 4;
#pragma unroll 8
  for (int j = j0; j < j1; ++j) {
    u64 kj = kb[j];  // wave-uniform address -> scalar load
    cnt += (kj > myk) ? 1 : 0;
  }
  __shared__ unsigned short part[4][256];
  part[q][r] = (unsigned short)cnt;
  __syncthreads();
  if (threadIdx.x < 256) {
    int rank = part[0][r] + part[1][r] + part[2][r] + part[3][r];
    order[(size_t)b * NN + rank] = i;
    sbox[(size_t)b * NN + rank] = boxes[(size_t)b * NN + i];
    if (vbyte[(size_t)b * NN + i])
      atomicOr(&vbits[b * 128 + (rank >> 6)], 1ull << (rank & 63));
  }
}

// 64x64 tile of the (sorted-order) suppression matrix: bit j set in row i's
// word iff j>i and IoU>0.5. Upper triangle only. Tiles with bx-by in {0..3}
// also write the COMPACT dnm array (diag + 3 next words) so reduce's wave 0
// prefetches with coalesced 512B loads.
__global__ __launch_bounds__(64) void build_kernel(
    const float4* __restrict__ sbox, u64* __restrict__ mask,
    u64* __restrict__ dnm) {
  int bx = blockIdx.x, by = blockIdx.y, b = blockIdx.z;
  if (bx < by) return;
  int lane = threadIdx.x;
  __shared__ float4 cb[64];
  cb[lane] = sbox[(size_t)b * NN + bx * 64 + lane];
  __syncthreads();
  int i = by * 64 + lane;
  float4 rb = sbox[(size_t)b * NN + i];
  u64 word = 0;
  int j0 = (bx == by) ? lane + 1 : 0;
  for (int jj = j0; jj < 64; ++jj)
    if (iou_pair(rb, cb[jj]) > 0.5f) word |= 1ull << jj;
  mask[((size_t)b * ROWS + i) * 128 + bx] = word;
  int dq = bx - by;
  if (dq < 4) dnm[(((size_t)b * 128 + by) * 4 + dq) * 64 + lane] = word;
}

struct TSet {
  ulonglong2 t0, t1, t2, t3, t4, t5, t6, t7, t8, t9;
};

// Greedy reduce v7: one 512-thread block per batch, one lgkm-only barrier
// per chunk; background pipeline has TWO chunks of load slack.
//  - Wave 0: scalar greedy bit-loop on prefetched diag words (4 rotating
//    named slots, filled from compact dnm with coalesced loads 2 chunks
//    ahead); kept lanes deposit words c+1..c+3 via LDS atomicOr.
//  - Waves 1..7: at chunk c ISSUE rows of chunk c-1 (rowlist published at
//    c-1) into register set U/V (alternating by body parity); CONSUME the
//    set issued at c-2 (rows of chunk c-3) into words > c. Deposits land
//    at c+1 >= the first word (k+4) not covered by wave 0 (k+1..k+3).
__global__ __launch_bounds__(512) void reduce_kernel(
    u64* __restrict__ mask, const u64* __restrict__ vbits,
    const u64* __restrict__ dnm, const int* __restrict__ order,
    float* __restrict__ keep_out) {
  int b = blockIdx.x, tid = threadIdx.x;
  int lane = tid & 63, wave = tid >> 6;
  __shared__ u64 s_remv[128];
  __shared__ u64 s_keep[128];
  __shared__ int s_rowlist[2][80];
  __shared__ int s_nk[2];
  u64* mbz = mask + (size_t)b * ROWS * 128;
  const u64* mb = mbz;
  const u64* dn = dnm + (size_t)b * 128 * 4 * 64;

  for (int w = tid; w < 128; w += 512) {
    s_remv[w] = 0ull;
    mbz[(size_t)NN * 128 + w] = 0ull;  // zero row (padded rowlist target)
  }
  if (tid < 2) s_nk[tid] = 0;
  if (tid < 160) s_rowlist[tid / 80][tid % 80] = NN;

  // Wave 0 state: vbits in regs; 4 rotating prefetch slots of (d,n,m,o).
  u64 va = 0, vb2 = 0;
  u64 dA = 0, nA = 0, mA = 0, oA = 0, dB = 0, nB = 0, mB = 0, oB = 0;
  u64 dC = 0, nC = 0, mC = 0, oC = 0, dD = 0, nD = 0, mD = 0, oD = 0;
  if (wave == 0) {
    va = vbits[b * 128 + 2 * lane];
    vb2 = vbits[b * 128 + 2 * lane + 1];
    const u64* r0 = dn + lane;  // chunk 0
    dA = r0[0]; nA = r0[64]; mA = r0[128]; oA = r0[192];
    const u64* r1 = dn + 4 * 64 + lane;  // chunk 1
    dB = r1[0]; nB = r1[64]; mB = r1[128]; oB = r1[192];
  }
  TSet U{}, V{};  // background in-flight sets (even / odd bodies)
  int w0i = 2 * lane, w1i = 2 * lane + 1;
  __syncthreads();  // full barrier: zero-row global write + LDS init visible

  // Serial body for chunk c: use (dcur..ocur); prefetch chunk c+2 into the
  // (c+2)%4 slot (its previous value died at body c-2) -> no copies/selects.
  auto serial_body = [&](int c, u64 dcur, u64 ncur, u64 mcur, u64 ocur,
                         u64& dnew, u64& nnew, u64& mnew, u64& onew) {
    if (c + 2 < 128) {  // issue first, consume 2 chunks later
      const u64* rp = dn + (size_t)(c + 2) * 4 * 64 + lane;
      dnew = rp[0]; nnew = rp[64]; mnew = rp[128]; onew = rp[192];
    } else {
      dnew = 0; nnew = 0; mnew = 0; onew = 0;
    }
    int par = c & 1;
    u64 rm = s_remv[c];  // LDS broadcast read
    u64 vbw = readlane64(par ? vb2 : va, c >> 1);
    u64 cand = readfirstlane64(vbw & ~rm);  // -> SALU loop
    u64 kept = 0;
    while (cand) {
      int bi = (int)__builtin_ctzll(cand);
      u64 rd = readlane64(dcur, bi);
      kept |= 1ull << bi;
      cand = (cand - 1) & cand & ~rd;
    }
    bool isk = (kept >> lane) & 1;
    if (c + 1 < 128 && isk && ncur) atomicOr(&s_remv[c + 1], ncur);
    if (c + 2 < 128 && isk && mcur) atomicOr(&s_remv[c + 2], mcur);
    if (c + 3 < 128 && isk && ocur) atomicOr(&s_remv[c + 3], ocur);
    s_rowlist[par][lane] = NN;  // pad; kept positions overwrite below
    if (isk) {
      int pos = __popcll(kept & ((1ull << lane) - 1ull));
      s_rowlist[par][pos] = c * 64 + lane;
    }
    if (lane == 0) {
      s_keep[c] = kept;
      s_nk[par] = __popcll(kept);
    }
  };

  auto bg_body = [&](int c, TSet& T) {
    // consume T (rows of chunk c-3, issued at body c-2) into words > c
    u64 ax = T.t0.x | T.t1.x | T.t2.x | T.t3.x | T.t4.x | T.t5.x | T.t6.x |
             T.t7.x | T.t8.x | T.t9.x;
    u64 ay = T.t0.y | T.t1.y | T.t2.y | T.t3.y | T.t4.y | T.t5.y | T.t6.y |
             T.t7.y | T.t8.y | T.t9.y;
    if (w0i > c && ax) atomicOr(&s_remv[w0i], ax);
    if (w1i > c && ay) atomicOr(&s_remv[w1i], ay);
    // issue loads for rows of chunk c-1 (consumed at body c+2, words > c+2)
    int nk1 = s_nk[(c - 1) & 1];  // c=0 -> slot 1 = 0
    T = TSet{};
    if (nk1 > 0 && w1i > c + 2) {
      const int* rl = s_rowlist[(c - 1) & 1];
      int base = wave - 1;  // waves 1..7 -> 0..6; stride 7 covers 0..69
      int r0 = rl[base], r1 = rl[base + 7], r2 = rl[base + 14],
          r3 = rl[base + 21], r4 = rl[base + 28], r5 = rl[base + 35],
          r6 = rl[base + 42], r7 = rl[base + 49], r8 = rl[base + 56],
          r9 = rl[base + 63];
      T.t0 = *(const ulonglong2*)(mb + (size_t)r0 * 128 + w0i);
      T.t1 = *(const ulonglong2*)(mb + (size_t)r1 * 128 + w0i);
      T.t2 = *(const ulonglong2*)(mb + (size_t)r2 * 128 + w0i);
      T.t3 = *(const ulonglong2*)(mb + (size_t)r3 * 128 + w0i);
      T.t4 = *(const ulonglong2*)(mb + (size_t)r4 * 128 + w0i);
      T.t5 = *(const ulonglong2*)(mb + (size_t)r5 * 128 + w0i);
      T.t6 = *(const ulonglong2*)(mb + (size_t)r6 * 128 + w0i);
      T.t7 = *(const ulonglong2*)(mb + (size_t)r7 * 128 + w0i);
      T.t8 = *(const ulonglong2*)(mb + (size_t)r8 * 128 + w0i);
      T.t9 = *(const ulonglong2*)(mb + (size_t)r9 * 128 + w0i);
    }
  };

  for (int c = 0; c < 128; c += 4) {
    if (wave == 0) serial_body(c, dA, nA, mA, oA, dC, nC, mC, oC);
    else bg_body(c, U);
    lbar();
    if (wave == 0) serial_body(c + 1, dB, nB, mB, oB, dD, nD, mD, oD);
    else bg_body(c + 1, V);
    lbar();
    if (wave == 0) serial_body(c + 2, dC, nC, mC, oC, dA, nA, mA, oA);
    else bg_body(c + 2, U);
    lbar();
    if (wave == 0) serial_body(c + 3, dD, nD, mD, oD, dB, nB, mB, oB);
    else bg_body(c + 3, V);
    lbar();
  }

  // scatter keep flags back to original anchor order
  for (int p = tid; p < NN; p += 512) {
    int orig = order[(size_t)b * NN + p];
    keep_out[(size_t)b * NN + orig] =
        ((s_keep[p >> 6] >> (p & 63)) & 1) ? 1.0f : 0.0f;
  }
}

// Slow-but-correct fallback if d_ws can't hold the mask: classic iterative
// greedy NMS, one block per batch.
__global__ __launch_bounds__(1024) void nms_fallback(
    const float4* __restrict__ sbox, const u64* __restrict__ vbits,
    const int* __restrict__ order, float* __restrict__ keep_out) {
  int b = blockIdx.x, tid = threadIdx.x;
  __shared__ u64 dead[128];
  __shared__ int s_next;
  __shared__ float4 s_box;
  for (int w = tid; w < 128; w += 1024) dead[w] = ~vbits[b * 128 + w];
  for (int p = tid; p < NN; p += 1024)
    keep_out[(size_t)b * NN + order[(size_t)b * NN + p]] = 0.0f;
  __syncthreads();
  int i = 0;
  while (true) {
    if (tid == 0) {
      int nxt = NN;
      int w = i >> 6;
      u64 live = ~dead[w] & (~0ull << (i & 63));
      while (true) {
        if (live) { nxt = w * 64 + __builtin_ctzll(live); break; }
        if (++w >= 128) break;
        live = ~dead[w];
      }
      s_next = nxt;
      if (nxt < NN) {
        s_box = sbox[(size_t)b * NN + nxt];
        keep_out[(size_t)b * NN + order[(size_t)b * NN + nxt]] = 1.0f;
      }
    }
    __syncthreads();
    i = s_next;
    if (i >= NN) break;
    float4 kb = s_box;
    for (int j = i + 1 + tid; j < NN; j += 1024) {
      if (iou_pair(kb, sbox[(size_t)b * NN + j]) > 0.5f)
        atomicOr(&dead[j >> 6], 1ull << (j & 63));
    }
    __syncthreads();
    i = i + 1;
  }
}

extern "C" void kernel_launch(void* const* d_in, const int* in_sizes, int n_in,
                              void* d_out, int out_size, void* d_ws, size_t ws_size,
                              hipStream_t stream) {
  const float* logits = (const float*)d_in[0];
  const float4* deltas = (const float4*)d_in[1];
  const float4* anchors = (const float4*)d_in[2];
  float* out = (float*)d_out;
  float4* boxes_out = (float4*)(out + OFF_BOXES);
  float* scores_out = out + OFF_SCORES;
  float* labels_out = out + OFF_LABELS;
  float* keep_out = out + OFF_KEEP;
  float* all_out = out + OFF_ALL;

  char* ws = (char*)d_ws;
  u64* keys = (u64*)(ws + WS_KEYS);
  unsigned char* vbyte = (unsigned char*)(ws + WS_VBYTE);
  int* order = (int*)(ws + WS_ORDER);
  float4* sbox = (float4*)(ws + WS_SBOX);
  u64* vbits = (u64*)(ws + WS_VBITS);
  u64* mask = (u64*)(ws + WS_MASK);
  u64* dnm = (u64*)(ws + WS_DNM);

  decode_kernel<<<dim3(NB * NN / 4), dim3(256), 0, stream>>>(
      logits, deltas, anchors, boxes_out, scores_out, labels_out, all_out,
      keys, vbyte, vbits);
  rank_kernel<<<dim3(NN / 256, NB), dim3(1024), 0, stream>>>(
      keys, (const float4*)boxes_out, vbyte, order, sbox, vbits, dnm);
  if (ws_size >= WS_TOTAL) {
    build_kernel<<<dim3(128, 128, NB), dim3(64), 0, stream>>>(sbox, mask, dnm);
    reduce_kernel<<<dim3(NB), dim3(512), 0, stream>>>(mask, vbits, dnm, order,
                                                      keep_out);
  } else {
    nms_fallback<<<dim3(NB), dim3(1024), 0, stream>>>(sbox, vbits, order,
                                                      keep_out);
  }
}